// Round 5
// baseline (306.717 us; speedup 1.0000x reference)
//
#include <hip/hip_runtime.h>

typedef __attribute__((ext_vector_type(8))) short short8;
typedef __attribute__((ext_vector_type(4))) float f32x4;
typedef __attribute__((ext_vector_type(4))) unsigned short u16x4;

#define B_   2
#define C_   192
#define NH_  4
#define HD_  48
#define CO_  576
#define HGT_ 256
#define WID_ 256
#define NSP_ 65536

__device__ __forceinline__ unsigned short f2bf(float f) {
  unsigned int u = __float_as_uint(f);
  u += 0x7FFFu + ((u >> 16) & 1u);   // RNE; inputs are normal floats
  return (unsigned short)(u >> 16);
}
__device__ __forceinline__ float bf2f(unsigned short h) {
  return __uint_as_float(((unsigned int)h) << 16);
}
__device__ __forceinline__ int swz(int n) { return (n & 7) ^ ((n >> 3) & 7); }

// ---------------------------------------------------------------- K0: qkv_w fp32 -> bf16, permuted to MFMA-fragment-linear order
// A_perm[(((m>>4)*6 + (k>>5))*4 + ((k>>3)&3))*16 + (m&15)]*8 + (k&7)] = A[m][k]
__global__ void k_cvtA(const float* __restrict__ src, unsigned short* __restrict__ dst) {
  int i = blockIdx.x * 256 + threadIdx.x;
  if (i >= CO_ * C_) return;
  int m = i / C_, k = i % C_;
  int f = m >> 4, l15 = m & 15, kk = k >> 5, lg = (k >> 3) & 3, j = k & 7;
  dst[((((f * 6 + kk) * 4 + lg) * 16 + l15) << 3) + j] = f2bf(src[i]);
}

// ---------------------------------------------------------------- GEMM: out[b][m][n] = sum_k A[m][k] * X[b][k+chanOff][n]
// Aperm: bf16 fragment-linear (k_cvtA order). X: [b][.][NSP] fp32 or bf16.
// BM=192 (mb), BN=128, K=192 in 3 chunks of 64, double-buffered LDS (2x16KB).
// 512 threads = 8 waves (4m x 2n); wave tile 48x64 => 3x4 frags of 16x16x32
// MFMA, operands swapped so each lane's D holds 4 consecutive n.
template<int MBLOCKS, bool X_BF16, bool OUT_BF16>
__global__ __launch_bounds__(512, 4)
void k_gemm(const unsigned short* __restrict__ Aperm, long aBatchStride,
            const void* __restrict__ Xin, long xBatchStride, int xChanOff,
            void* __restrict__ Out, long outBatchStride)
{
  __shared__ unsigned short Xs[2][128 * 64];   // [buf][n][klocal], 16B-unit XOR swizzle
  const int tid = threadIdx.x;
  const int b = blockIdx.z;
  int mb, nb;
  if (MBLOCKS == 3) {                        // keep the 3 m-blocks sharing an X panel on one XCD
    int lin = blockIdx.x;
    int xcd = lin & 7, rest = lin >> 3;
    mb = rest % 3; nb = (rest / 3) * 8 + xcd;
  } else { mb = 0; nb = blockIdx.x; }

  // staging subtile: each thread owns one 4k x 4n subtile per chunk
  const int sn = tid & 31, sk = tid >> 5;
  const int n0 = sn * 4, k0s = sk * 4;
  const int u16 = sk >> 1, hh = sk & 1;

  const float* Xf = (const float*)Xin + (size_t)b * xBatchStride +
                    (size_t)xChanOff * NSP_ + (size_t)nb * 128 + n0;
  const unsigned short* Xh = (const unsigned short*)Xin + (size_t)b * xBatchStride +
                    (size_t)xChanOff * NSP_ + (size_t)nb * 128 + n0;

  f32x4 rf[4];
  u16x4 rh[4];

  auto LOADC = [&](int c) {
    if (!X_BF16) {
      const float* p = Xf + (size_t)(c * 64 + k0s) * NSP_;
      rf[0] = *(const f32x4*)(p);
      rf[1] = *(const f32x4*)(p + NSP_);
      rf[2] = *(const f32x4*)(p + 2 * NSP_);
      rf[3] = *(const f32x4*)(p + 3 * NSP_);
    } else {
      const unsigned short* p = Xh + (size_t)(c * 64 + k0s) * NSP_;
      rh[0] = *(const u16x4*)(p);
      rh[1] = *(const u16x4*)(p + NSP_);
      rh[2] = *(const u16x4*)(p + 2 * NSP_);
      rh[3] = *(const u16x4*)(p + 3 * NSP_);
    }
  };
  auto WRITEC = [&](int buf) {               // 4x4 in-register transpose -> Xs[n][k]
#pragma unroll
    for (int j = 0; j < 4; j++) {
      int n = n0 + j;
      u16x4 w;
      if (!X_BF16) { w[0] = f2bf(rf[0][j]); w[1] = f2bf(rf[1][j]);
                     w[2] = f2bf(rf[2][j]); w[3] = f2bf(rf[3][j]); }
      else         { w[0] = rh[0][j]; w[1] = rh[1][j]; w[2] = rh[2][j]; w[3] = rh[3][j]; }
      *(u16x4*)&Xs[buf][n * 64 + ((u16 ^ swz(n)) << 3) + (hh << 2)] = w;
    }
  };

  const int wave = tid >> 6, lane = tid & 63;
  const int wm = wave >> 1, wn = wave & 1;
  const int l15 = lane & 15, lg = lane >> 4;
  const int fragM0 = mb * 12 + wm * 3;       // A frag index base (16-row units)
  const int colbase = wn * 64;
  const unsigned short* Ap = Aperm + (size_t)b * aBatchStride;

  f32x4 acc[3][4];
#pragma unroll
  for (int i = 0; i < 3; i++)
#pragma unroll
    for (int j = 0; j < 4; j++) acc[i][j] = (f32x4){0.f, 0.f, 0.f, 0.f};

  LOADC(0);
  WRITEC(0);
  __syncthreads();

#pragma unroll
  for (int c = 0; c < 3; c++) {
    // A-frags for this chunk first (their vmcnt retires before the X prefetch)
    short8 af[2][3];
#pragma unroll
    for (int kk2 = 0; kk2 < 2; kk2++)
#pragma unroll
      for (int fm = 0; fm < 3; fm++)
        af[kk2][fm] = *(const short8*)(Ap +
            (((size_t)((fragM0 + fm) * 6 + c * 2 + kk2) * 64 + lane) << 3));
    if (c < 2) LOADC(c + 1);                 // prefetch next chunk into regs
#pragma unroll
    for (int kk2 = 0; kk2 < 2; kk2++) {
      const int u = kk2 * 4 + lg;
      short8 bfr[4];
#pragma unroll
      for (int fn = 0; fn < 4; fn++) {
        int col = colbase + fn * 16 + l15;
        bfr[fn] = *(const short8*)(&Xs[c & 1][col * 64 + ((u ^ swz(col)) << 3)]);
      }
      __builtin_amdgcn_s_setprio(1);
#pragma unroll
      for (int fm = 0; fm < 3; fm++)
#pragma unroll
        for (int fn = 0; fn < 4; fn++)   // swapped operands: D rows = n, cols = m
          acc[fm][fn] = __builtin_amdgcn_mfma_f32_16x16x32_bf16(bfr[fn], af[kk2][fm], acc[fm][fn], 0, 0, 0);
      __builtin_amdgcn_s_setprio(0);
    }
    if (c < 2) { WRITEC((c + 1) & 1); __syncthreads(); }
  }

  // D layout (swapped): lane l15 = m-row (within frag), lg*4+r = n-col -> 4 consecutive n per lane
  const size_t ncol0 = (size_t)nb * 128 + colbase;
  if (OUT_BF16) {
    unsigned short* O = (unsigned short*)Out + (size_t)b * outBatchStride;
#pragma unroll
    for (int fm = 0; fm < 3; fm++) {
      int m = (fragM0 + fm) * 16 + l15;
#pragma unroll
      for (int fn = 0; fn < 4; fn++) {
        u16x4 w;
        w[0] = f2bf(acc[fm][fn][0]); w[1] = f2bf(acc[fm][fn][1]);
        w[2] = f2bf(acc[fm][fn][2]); w[3] = f2bf(acc[fm][fn][3]);
        *(u16x4*)(O + (size_t)m * NSP_ + ncol0 + fn * 16 + lg * 4) = w;
      }
    }
  } else {
    float* O = (float*)Out + (size_t)b * outBatchStride;
#pragma unroll
    for (int fm = 0; fm < 3; fm++) {
      int m = (fragM0 + fm) * 16 + l15;
#pragma unroll
      for (int fn = 0; fn < 4; fn++)
        *(f32x4*)(O + (size_t)m * NSP_ + ncol0 + fn * 16 + lg * 4) = acc[fm][fn];
    }
  }
}

// ---------------------------------------------------------------- K2: depthwise 3x3 (pad 1) + sumsq of q,k channels
// No LDS staging: short8 vector loads, horizontal halo via __shfl within
// 32-lane groups, vertical halo via rolling 3-row register window.
#define DW_RT 16
__global__ __launch_bounds__(256)
void k_dw(const unsigned short* __restrict__ qkv, const float* __restrict__ dww,
          unsigned short* __restrict__ out, float* __restrict__ sumsq)
{
  const int ch = blockIdx.y;
  const int b  = blockIdx.z;
  const int tid = threadIdx.x;
  const int seg = tid & 31;                  // column segment (8 px)
  const int rb  = tid >> 5;                  // row-block 0..7
  const int ybase = blockIdx.x * (8 * DW_RT) + rb * DW_RT;

  const unsigned short* in = qkv + ((size_t)b * CO_ + ch) * NSP_;
  unsigned short* o = out + ((size_t)b * CO_ + ch) * NSP_;
  float w[9];
#pragma unroll
  for (int i = 0; i < 9; i++) w[i] = dww[ch * 9 + i];

  float rw[3][10];
  float ss = 0.f;
#pragma unroll
  for (int i = 0; i < DW_RT + 2; i++) {
    const int yy = ybase - 1 + i;
    float* f = rw[i % 3];
    if ((unsigned)yy < (unsigned)HGT_) {
      short8 v = *(const short8*)(in + (size_t)yy * WID_ + seg * 8);
#pragma unroll
      for (int j = 0; j < 8; j++) f[j + 1] = bf2f((unsigned short)v[j]);
    } else {
#pragma unroll
      for (int j = 0; j < 8; j++) f[j + 1] = 0.f;
    }
    float lf = __shfl_up(f[8], 1, 32);
    float rt = __shfl_down(f[1], 1, 32);
    f[0] = (seg == 0)  ? 0.f : lf;
    f[9] = (seg == 31) ? 0.f : rt;
    if (i >= 2) {
      const float* a  = rw[(i - 2) % 3];
      const float* bb = rw[(i - 1) % 3];
      const float* cc = f;
      short8 ov;
#pragma unroll
      for (int j = 0; j < 8; j++) {
        float acc = a[j]  * w[0] + a[j + 1]  * w[1] + a[j + 2]  * w[2]
                  + bb[j] * w[3] + bb[j + 1] * w[4] + bb[j + 2] * w[5]
                  + cc[j] * w[6] + cc[j + 1] * w[7] + cc[j + 2] * w[8];
        ov[j] = (short)f2bf(acc);
        ss += acc * acc;
      }
      *(short8*)(o + (size_t)(yy - 1) * WID_ + seg * 8) = ov;
    }
  }

  if (ch < 2 * C_) {                          // only q,k channels need norms
#pragma unroll
    for (int off = 32; off > 0; off >>= 1) ss += __shfl_down(ss, off);
    __shared__ float wsum[4];
    if ((tid & 63) == 0) wsum[tid >> 6] = ss;
    __syncthreads();
    if (tid == 0) atomicAdd(&sumsq[b * 2 * C_ + ch], wsum[0] + wsum[1] + wsum[2] + wsum[3]);
  }
}

// ---------------------------------------------------------------- K3: per-(b,h) q.k^T partials over n-chunks (MFMA)
// 4 waves x 256 spatial each, then cross-wave LDS reduce -> ONE partial tile per block.
__global__ __launch_bounds__(256)
void k_qk(const unsigned short* __restrict__ qkvd, float* __restrict__ part)
{
  const int chunk = blockIdx.x;               // 64 chunks of 1024 n
  const int h = blockIdx.y, b = blockIdx.z;
  const int tid = threadIdx.x;
  const int wave = tid >> 6, lane = tid & 63;
  const int l15 = lane & 15, lg = lane >> 4;
  const unsigned short* qb = qkvd + (size_t)b * CO_ * NSP_ + (size_t)(h * HD_) * NSP_;
  const unsigned short* kb = qkvd + (size_t)b * CO_ * NSP_ + (size_t)(C_ + h * HD_) * NSP_;
  const int kbase = chunk * 1024 + wave * 256;

  f32x4 acc[3][3];
#pragma unroll
  for (int i = 0; i < 3; i++)
#pragma unroll
    for (int j = 0; j < 3; j++) acc[i][j] = (f32x4){0.f, 0.f, 0.f, 0.f};

#pragma unroll
  for (int ks = 0; ks < 8; ks++) {
    const int k0 = kbase + ks * 32 + lg * 8;
    short8 af[3], bfr[3];
#pragma unroll
    for (int i = 0; i < 3; i++)
      af[i] = *(const short8*)(qb + (size_t)(i * 16 + l15) * NSP_ + k0);
#pragma unroll
    for (int i = 0; i < 3; i++)
      bfr[i] = *(const short8*)(kb + (size_t)(i * 16 + l15) * NSP_ + k0);
#pragma unroll
    for (int fm = 0; fm < 3; fm++)
#pragma unroll
      for (int fn = 0; fn < 3; fn++)
        acc[fm][fn] = __builtin_amdgcn_mfma_f32_16x16x32_bf16(af[fm], bfr[fn], acc[fm][fn], 0, 0, 0);
  }

  __shared__ float red[4][HD_ * HD_];
#pragma unroll
  for (int fm = 0; fm < 3; fm++)
#pragma unroll
    for (int fn = 0; fn < 3; fn++)
#pragma unroll
      for (int r = 0; r < 4; r++)
        red[wave][(fm * 16 + lg * 4 + r) * HD_ + fn * 16 + l15] = acc[fm][fn][r];
  __syncthreads();

  float* P = part + ((size_t)(b * NH_ + h) * 64 + chunk) * (HD_ * HD_);
#pragma unroll
  for (int j = 0; j < 9; j++) {               // 2304 = 9*256
    int e = tid + j * 256;
    P[e] = red[0][e] + red[1][e] + red[2][e] + red[3][e];
  }
}

// ---------------------------------------------------------------- K4: reduce 64 partials (thread-parallel, 9-way ILP),
//      scale by 1/(|q||k|)*temp, softmax, compose M[b] = proj_w @ blockdiag(attn)
//      stored fragment-permuted bf16
__global__ __launch_bounds__(256)
void k_smax(const float* __restrict__ part, const float* __restrict__ sumsq,
            const float* __restrict__ temp, const float* __restrict__ projw,
            unsigned short* __restrict__ M)
{
  const int h = blockIdx.x, b = blockIdx.y;
  const int tid = threadIdx.x;
  __shared__ float lgt[HD_][HD_];
  __shared__ float at[HD_][HD_];
  __shared__ float pw[C_][HD_];
  const float tmp = temp[h];
  const float* P = part + (size_t)(b * NH_ + h) * 64 * (HD_ * HD_);

  float s[9];
#pragma unroll
  for (int j = 0; j < 9; j++) s[j] = 0.f;
  for (int p = 0; p < 64; p++) {
    const float* Pp = P + (size_t)p * (HD_ * HD_);
#pragma unroll
    for (int j = 0; j < 9; j++) s[j] += Pp[tid + j * 256];
  }
#pragma unroll
  for (int j = 0; j < 9; j++) {
    int e = tid + j * 256;
    int c = e / HD_, d = e % HD_;
    float nq = fmaxf(sqrtf(sumsq[b * 2 * C_ + h * HD_ + c]), 1e-12f);
    float nk = fmaxf(sqrtf(sumsq[b * 2 * C_ + C_ + h * HD_ + d]), 1e-12f);
    lgt[c][d] = s[j] / (nq * nk) * tmp;
  }
  for (int e = tid; e < C_ * HD_; e += 256) {
    int o = e / HD_, c = e % HD_;
    pw[o][c] = projw[o * C_ + h * HD_ + c];
  }
  __syncthreads();
  if (tid < HD_) {
    float mx = -1e30f;
    for (int d = 0; d < HD_; d++) mx = fmaxf(mx, lgt[tid][d]);
    float ssum = 0.f;
    for (int d = 0; d < HD_; d++) { float e_ = expf(lgt[tid][d] - mx); at[tid][d] = e_; ssum += e_; }
    float inv = 1.f / ssum;
    for (int d = 0; d < HD_; d++) at[tid][d] *= inv;
  }
  __syncthreads();
  unsigned short* Mo = M + (size_t)b * C_ * C_;
  for (int e = tid; e < C_ * HD_; e += 256) {
    int o = e / HD_, d = e % HD_;
    float sm = 0.f;
    for (int c = 0; c < HD_; c++) sm += pw[o][c] * at[c][d];
    int col = h * HD_ + d;                    // fragment-permuted index (see k_cvtA)
    int f = o >> 4, l15 = o & 15, kk = col >> 5, lg = (col >> 3) & 3, j = col & 7;
    Mo[((((f * 6 + kk) * 4 + lg) * 16 + l15) << 3) + j] = f2bf(sm);
  }
}

// ----------------------------------------------------------------
extern "C" void kernel_launch(void* const* d_in, const int* in_sizes, int n_in,
                              void* d_out, int out_size, void* d_ws, size_t ws_size,
                              hipStream_t stream)
{
  const float* x     = (const float*)d_in[0];
  const float* qkvw  = (const float*)d_in[1];
  const float* dww   = (const float*)d_in[2];
  const float* projw = (const float*)d_in[3];
  const float* temp  = (const float*)d_in[4];
  float* out         = (float*)d_out;

  char* ws = (char*)d_ws;
  size_t off = 0;
  auto alloc = [&](size_t bytes) { void* p = ws + off; off += (bytes + 255) & ~(size_t)255; return p; };
  unsigned short* qkvw_bf = (unsigned short*)alloc((size_t)CO_ * C_ * 2);
  unsigned short* M_bf    = (unsigned short*)alloc((size_t)B_ * C_ * C_ * 2);
  float* sumsq            = (float*)alloc((size_t)B_ * 2 * C_ * 4);
  float* part             = (float*)alloc((size_t)B_ * NH_ * 64 * HD_ * HD_ * 4);
  unsigned short* qkv_bf  = (unsigned short*)alloc((size_t)B_ * CO_ * NSP_ * 2);
  unsigned short* qkvd_bf = (unsigned short*)alloc((size_t)B_ * CO_ * NSP_ * 2);

  hipMemsetAsync(sumsq, 0, (size_t)B_ * 2 * C_ * 4, stream);
  k_cvtA<<<dim3((CO_ * C_ + 255) / 256), dim3(256), 0, stream>>>(qkvw, qkvw_bf);
  // K1: qkv = qkv_w @ x    (M=576 via 3 m-blocks, bf16 out)
  k_gemm<3, false, true><<<dim3(3 * 512, 1, B_), dim3(512), 0, stream>>>(
      qkvw_bf, 0, x, (long)C_ * NSP_, 0, qkv_bf, (long)CO_ * NSP_);
  // K2: depthwise 3x3 + q/k sum-of-squares (vectorized, no LDS)
  k_dw<<<dim3(HGT_ / (8 * DW_RT), CO_, B_), dim3(256), 0, stream>>>(qkv_bf, dww, qkvd_bf, sumsq);
  // K3: q.k^T partials (cross-wave reduced: 64 tiles per (b,h))
  k_qk<<<dim3(64, NH_, B_), dim3(256), 0, stream>>>(qkvd_bf, part);
  // K4: softmax + fold proj_w -> M[b] (192x192 bf16, fragment-permuted)
  k_smax<<<dim3(NH_, B_), dim3(256), 0, stream>>>(part, sumsq, temp, projw, M_bf);
  // K5: out = M[b] @ v   (fp32 out to d_out)
  k_gemm<1, true, false><<<dim3(512, 1, B_), dim3(512), 0, stream>>>(
      M_bf, (long)C_ * C_, qkvd_bf, (long)CO_ * NSP_, 2 * C_, out, (long)C_ * NSP_);
}